// Round 14
// baseline (200.501 us; speedup 1.0000x reference)
//
#include <hip/hip_runtime.h>

#define BB 16
#define TT 1024
#define HH 8
#define DD 64
#define NF 512

typedef __attribute__((ext_vector_type(4))) float f4;
typedef __attribute__((ext_vector_type(8))) short s8;
typedef __attribute__((ext_vector_type(2))) unsigned int u32x2;
typedef unsigned short u16;
typedef unsigned int u32;

#define LOG2E 1.4426950408889634f

__device__ __forceinline__ u16 f2bf(float x){
    unsigned int u = __builtin_bit_cast(unsigned int, x);
    u = (u + 0x7FFFu + ((u >> 16) & 1u)) >> 16;
    return (u16)u;
}
__device__ __forceinline__ float bf2f(u16 h){
    unsigned int u = ((unsigned int)h) << 16;
    return __builtin_bit_cast(float, u);
}
__device__ __forceinline__ u32 cvt_pk(float a, float b){
    u32 r; asm("v_cvt_pk_bf16_f32 %0, %1, %2" : "=v"(r) : "v"(a), "v"(b)); return r;
}
__device__ __forceinline__ float lo_bf(u32 p){ return __builtin_bit_cast(float, p << 16); }
__device__ __forceinline__ float hi_bf(u32 p){ return __builtin_bit_cast(float, p & 0xFFFF0000u); }

// ---------------------------------------------------------------------------
// Weight prep: Wt[n][k] = bf16(W[k][n]) for Wq,Wk,Wv,Wpos; Wo -> hi/lo pair.
// ---------------------------------------------------------------------------
__global__ __launch_bounds__(256) void prep_w(const float* __restrict__ Wq,
    const float* __restrict__ Wk, const float* __restrict__ Wv,
    const float* __restrict__ Wpos, const float* __restrict__ Wo,
    u16* __restrict__ wtq, u16* __restrict__ wtk, u16* __restrict__ wtv,
    u16* __restrict__ wtp, u16* __restrict__ wohi, u16* __restrict__ wolo)
{
    __shared__ float tile[32][33];
    const int which = blockIdx.z;
    const float* W = which==0?Wq:which==1?Wk:which==2?Wv:which==3?Wpos:Wo;
    const int n0 = blockIdx.x*32, k0 = blockIdx.y*32;
    const int tc = threadIdx.x & 31, tr = threadIdx.x >> 5;
#pragma unroll
    for (int i=0;i<4;i++){ int r = tr + i*8; tile[r][tc] = W[(size_t)(k0+r)*NF + n0+tc]; }
    __syncthreads();
#pragma unroll
    for (int i=0;i<4;i++){
        int n = tr + i*8, k = tc;
        float val = tile[k][n];
        u16 hi = f2bf(val);
        size_t off = (size_t)(n0+n)*NF + k0+k;
        if (which==0) wtq[off]=hi; else if (which==1) wtk[off]=hi;
        else if (which==2) wtv[off]=hi; else if (which==3) wtp[off]=hi;
        else { wohi[off]=hi; wolo[off]=f2bf(val - bf2f(hi)); }
    }
}

// ---------------------------------------------------------------------------
// pos projection (round-8 2-barrier body, tiny grid): p = pos_emb@Wpos.
// ---------------------------------------------------------------------------
template<int MODE>
__global__ __launch_bounds__(256) void gemm_bf16(const float* __restrict__ A,
                                                 const u16* __restrict__ Wt,
                                                 u16* __restrict__ out)
{
    __shared__ __align__(16) u16 As[128*64];
    __shared__ __align__(16) u16 Bs[128*64];
    const int tid = threadIdx.x;
    const int row0 = blockIdx.x*128, col0 = blockIdx.y*128;
    const int wid = tid>>6, lane = tid&63, lm = lane&15, lg = lane>>4;
    const int wm = wid>>1, wn = wid&1;

    f4 acc[4][4];
#pragma unroll
    for (int i=0;i<4;i++)
#pragma unroll
        for (int j=0;j<4;j++) acc[i][j] = (f4){0.f,0.f,0.f,0.f};

    for (int k0=0;k0<NF;k0+=64){
        f4 areg[8]; s8 breg[4];
#pragma unroll
        for (int it=0; it<8; ++it){
            int idx = (it*256 + tid)*4;
            int m = idx>>6, k = idx&63;
            areg[it] = *(const f4*)(&A[(size_t)(row0+m)*NF + k0 + k]);
        }
#pragma unroll
        for (int it=0; it<4; ++it){
            int idx = (it*256 + tid)*8;
            int n = idx>>6, k = idx&63;
            breg[it] = *(const s8*)(&Wt[(size_t)(col0+n)*NF + k0 + k]);
        }
        __syncthreads();
#pragma unroll
        for (int it=0; it<8; ++it){
            int idx = (it*256+tid)*4;
            int m = idx>>6, k = idx&63;
            u32x2 pk;
            pk[0] = cvt_pk(areg[it][0], areg[it][1]);
            pk[1] = cvt_pk(areg[it][2], areg[it][3]);
            *(u32x2*)((char*)As + ((m*128 + k*2) ^ ((m&7)<<4))) = pk;
        }
#pragma unroll
        for (int it=0; it<4; ++it){
            int idx = (it*256+tid)*8;
            int n = idx>>6, k = idx&63;
            *(s8*)((char*)Bs + ((n*128 + k*2) ^ ((n&7)<<4))) = breg[it];
        }
        __syncthreads();
        s8 af[4][2], bf[4][2];
#pragma unroll
        for (int i=0;i<4;i++){
            int m = wm*64 + i*16 + lm;
#pragma unroll
            for (int c=0;c<2;c++)
                af[i][c] = *(const s8*)((char*)As + ((m*128 + c*64 + lg*16) ^ ((m&7)<<4)));
        }
#pragma unroll
        for (int j=0;j<4;j++){
            int n = wn*64 + j*16 + lm;
#pragma unroll
            for (int c=0;c<2;c++)
                bf[j][c] = *(const s8*)((char*)Bs + ((n*128 + c*64 + lg*16) ^ ((n&7)<<4)));
        }
#pragma unroll
        for (int i=0;i<4;i++)
#pragma unroll
            for (int j=0;j<4;j++)
#pragma unroll
                for (int c=0;c<2;c++)
                    acc[i][j] = __builtin_amdgcn_mfma_f32_16x16x32_bf16(af[i][c], bf[j][c], acc[i][j], 0,0,0);
    }

#pragma unroll
    for (int i=0;i<4;i++)
#pragma unroll
        for (int j=0;j<4;j++)
#pragma unroll
            for (int r=0;r<4;r++){
                const int m = row0 + wm*64 + i*16 + lg*4 + r;
                const int n = col0 + wn*64 + j*16 + lm;
                const int hh = n>>6, dd = n&63;
                out[(size_t)(hh*TT + m)*64 + dd] = f2bf(acc[i][j][r]);
            }
}

// ---------------------------------------------------------------------------
// Merged q/kp/vt projections — single-barrier double-buffered pipeline:
//   [bar] -> issue reg loads(k+1) -> compute(k) -> cvt+ds_write(k+1)->buf^1 -> [bar]
// Writes target the buffer whose readers finished before the TOP barrier (no
// race); load waits hide under the 32-MFMA compute. One barrier per K-iter.
// z=0: q = query@Wq+bq+pbu -> bhtd; z=1: kp = key@Wk+bk+p -> bhtd;
// z=2: vt = (value@Wv+bv)^T -> [bh][d][t].
// ---------------------------------------------------------------------------
#define QKV_LOADB(k0v) do{ _Pragma("unroll") for (int it=0; it<4; ++it){ \
    int idx = (it*256 + tid)*8; int n_ = idx>>6, kc_ = idx&63; \
    breg[it] = *(const s8*)(&Wt[(size_t)(col0+n_)*NF + (k0v) + kc_]); } }while(0)

#define QKV_LOADA(k0v) do{ _Pragma("unroll") for (int it=0; it<8; ++it){ \
    int idx = (it*256 + tid)*4; int m_ = idx>>6, kc_ = idx&63; \
    areg[it] = *(const f4*)(&A[(size_t)(row0+m_)*NF + (k0v) + kc_]); } }while(0)

#define QKV_WRITE(BUF) do{ \
  _Pragma("unroll") for (int it=0; it<8; ++it){ \
    int idx = (it*256+tid)*4; int m_ = idx>>6, kc_ = idx&63; \
    u32x2 pk_; pk_[0]=cvt_pk(areg[it][0],areg[it][1]); pk_[1]=cvt_pk(areg[it][2],areg[it][3]); \
    *(u32x2*)((char*)As[BUF] + ((m_*128 + kc_*2) ^ ((m_&7)<<4))) = pk_; } \
  _Pragma("unroll") for (int it=0; it<4; ++it){ \
    int idx = (it*256+tid)*8; int n_ = idx>>6, kc_ = idx&63; \
    *(s8*)((char*)Bs[BUF] + ((n_*128 + kc_*2) ^ ((n_&7)<<4))) = breg[it]; } }while(0)

#define QKV_COMPUTE(BUF) do{ s8 af[4][2], bf[4][2]; \
  _Pragma("unroll") for (int i=0;i<4;i++){ int m_ = wm*64 + i*16 + lm; \
    _Pragma("unroll") for (int c=0;c<2;c++) \
      af[i][c] = *(const s8*)((char*)As[BUF] + ((m_*128 + c*64 + lg*16) ^ ((m_&7)<<4))); } \
  _Pragma("unroll") for (int j=0;j<4;j++){ int n_ = wn*64 + j*16 + lm; \
    _Pragma("unroll") for (int c=0;c<2;c++) \
      bf[j][c] = *(const s8*)((char*)Bs[BUF] + ((n_*128 + c*64 + lg*16) ^ ((n_&7)<<4))); } \
  _Pragma("unroll") for (int i=0;i<4;i++) \
    _Pragma("unroll") for (int j=0;j<4;j++) \
      _Pragma("unroll") for (int c=0;c<2;c++) \
        acc[i][j] = __builtin_amdgcn_mfma_f32_16x16x32_bf16(af[i][c], bf[j][c], acc[i][j], 0,0,0); }while(0)

#define QKV_STEP(kk, CUR) do{ \
    if ((kk) < 7) { QKV_LOADB(((kk)+1)*64); QKV_LOADA(((kk)+1)*64); } \
    QKV_COMPUTE(CUR); \
    if ((kk) < 7) { QKV_WRITE((CUR)^1); __syncthreads(); } }while(0)

__global__ __launch_bounds__(256) void qkv_gemm(
    const float* __restrict__ Aq, const float* __restrict__ Ak, const float* __restrict__ Av,
    const u16* __restrict__ Wtq, const u16* __restrict__ Wtk, const u16* __restrict__ Wtv,
    const float* __restrict__ bq, const float* __restrict__ bk, const float* __restrict__ bv,
    const u16* __restrict__ padd, const float* __restrict__ pbu,
    u16* __restrict__ oq, u16* __restrict__ okp, u16* __restrict__ ovt)
{
    __shared__ __align__(16) u16 As[2][128*64];
    __shared__ __align__(16) u16 Bs[2][128*64];
    const int tid = threadIdx.x;
    const int z = blockIdx.z;
    const float* A    = z==0?Aq : z==1?Ak : Av;
    const u16*   Wt   = z==0?Wtq: z==1?Wtk: Wtv;
    const float* bias = z==0?bq : z==1?bk : bv;
    const int row0 = blockIdx.x*128, col0 = blockIdx.y*128;
    const int wid = tid>>6, lane = tid&63, lm = lane&15, lg = lane>>4;
    const int wm = wid>>1, wn = wid&1;

    f4 acc[4][4];
#pragma unroll
    for (int i=0;i<4;i++)
#pragma unroll
        for (int j=0;j<4;j++) acc[i][j] = (f4){0.f,0.f,0.f,0.f};

    f4 areg[8]; s8 breg[4];

    // prologue: stage tile 0 (latency exposed once)
    QKV_LOADB(0); QKV_LOADA(0);
    QKV_WRITE(0);
    __syncthreads();

    QKV_STEP(0,0); QKV_STEP(1,1); QKV_STEP(2,0); QKV_STEP(3,1);
    QKV_STEP(4,0); QKV_STEP(5,1); QKV_STEP(6,0); QKV_STEP(7,1);

#pragma unroll
    for (int i=0;i<4;i++){
#pragma unroll
        for (int j=0;j<4;j++){
#pragma unroll
            for (int r=0;r<4;r++){
                const int m = row0 + wm*64 + i*16 + lg*4 + r;
                const int n = col0 + wn*64 + j*16 + lm;
                float val = acc[i][j][r] + bias[n];
                const int hh = n>>6, dd = n&63;
                const int b_ = m>>10, t_ = m&1023;
                if (z == 0){
                    val += pbu[n];
                    oq[((size_t)(b_*HH+hh)*TT + t_)*64 + dd] = f2bf(val);
                } else if (z == 1){
                    val += bf2f(padd[(size_t)(hh*TT + t_)*64 + dd]);
                    okp[((size_t)(b_*HH+hh)*TT + t_)*64 + dd] = f2bf(val);
                } else {
                    ovt[(((size_t)(b_*HH+hh))*DD + dd)*TT + t_] = f2bf(val);
                }
            }
        }
    }
}

// ---------------------------------------------------------------------------
// Final GEMM (round-8): out = [aoh+aol] @ [Wo hi/lo] + bo, 3 MFMA terms.
// ---------------------------------------------------------------------------
__global__ __launch_bounds__(256) void gemm_final(const u16* __restrict__ Ahg,
    const u16* __restrict__ Alg,
    const u16* __restrict__ Bhg, const u16* __restrict__ Blg,
    const float* __restrict__ bias, float* __restrict__ out)
{
    __shared__ __align__(16) u16 Ah[128*64];
    __shared__ __align__(16) u16 Al[128*64];
    __shared__ __align__(16) u16 Bh[128*64];
    __shared__ __align__(16) u16 Bl[128*64];
    const int tid = threadIdx.x;
    const int row0 = blockIdx.x*128, col0 = blockIdx.y*128;
    const int wid = tid>>6, lane = tid&63, lm = lane&15, lg = lane>>4;
    const int wm = wid>>1, wn = wid&1;

    f4 acc[4][4];
#pragma unroll
    for (int i=0;i<4;i++)
#pragma unroll
        for (int j=0;j<4;j++) acc[i][j] = (f4){0.f,0.f,0.f,0.f};

    for (int k0=0;k0<NF;k0+=64){
        s8 ahreg[4], alreg[4], bhreg[4], blreg[4];
#pragma unroll
        for (int it=0; it<4; ++it){
            int idx = (it*256 + tid)*8;
            int m = idx>>6, k = idx&63;
            ahreg[it] = *(const s8*)(&Ahg[(size_t)(row0+m)*NF + k0 + k]);
            alreg[it] = *(const s8*)(&Alg[(size_t)(row0+m)*NF + k0 + k]);
            bhreg[it] = *(const s8*)(&Bhg[(size_t)(col0+m)*NF + k0 + k]);
            blreg[it] = *(const s8*)(&Blg[(size_t)(col0+m)*NF + k0 + k]);
        }
        __syncthreads();
#pragma unroll
        for (int it=0; it<4; ++it){
            int idx = (it*256+tid)*8;
            int m = idx>>6, k = idx&63;
            int off = (m*128 + k*2) ^ ((m&7)<<4);
            *(s8*)((char*)Ah + off) = ahreg[it];
            *(s8*)((char*)Al + off) = alreg[it];
            *(s8*)((char*)Bh + off) = bhreg[it];
            *(s8*)((char*)Bl + off) = blreg[it];
        }
        __syncthreads();
#pragma unroll
        for (int c=0;c<2;c++){
            s8 ah[4], al[4], bh4[4], bl4[4];
#pragma unroll
            for (int i=0;i<4;i++){
                int m = wm*64 + i*16 + lm;
                int off = (m*128 + c*64 + lg*16) ^ ((m&7)<<4);
                ah[i] = *(const s8*)((char*)Ah + off);
                al[i] = *(const s8*)((char*)Al + off);
            }
#pragma unroll
            for (int j=0;j<4;j++){
                int n = wn*64 + j*16 + lm;
                int off = (n*128 + c*64 + lg*16) ^ ((n&7)<<4);
                bh4[j] = *(const s8*)((char*)Bh + off);
                bl4[j] = *(const s8*)((char*)Bl + off);
            }
#pragma unroll
            for (int i=0;i<4;i++)
#pragma unroll
                for (int j=0;j<4;j++){
                    acc[i][j] = __builtin_amdgcn_mfma_f32_16x16x32_bf16(al[i], bh4[j], acc[i][j], 0,0,0);
                    acc[i][j] = __builtin_amdgcn_mfma_f32_16x16x32_bf16(ah[i], bl4[j], acc[i][j], 0,0,0);
                    acc[i][j] = __builtin_amdgcn_mfma_f32_16x16x32_bf16(ah[i], bh4[j], acc[i][j], 0,0,0);
                }
        }
    }

#pragma unroll
    for (int i=0;i<4;i++)
#pragma unroll
        for (int j=0;j<4;j++)
#pragma unroll
            for (int r=0;r<4;r++){
                const int m = row0 + wm*64 + i*16 + lg*4 + r;
                const int n = col0 + wn*64 + j*16 + lm;
                out[(size_t)m*NF + n] = acc[i][j][r] + bias[n];
            }
}

// ---------------------------------------------------------------------------
// sb[b,h,s] = (((v-u)·p[h,s])/8 + mask[b,s]) * log2(e).
// ---------------------------------------------------------------------------
__global__ __launch_bounds__(256) void sbias2(const u16* __restrict__ p,
                                              const float* __restrict__ pbu,
                                              const float* __restrict__ pbv,
                                              const float* __restrict__ mask,
                                              float* __restrict__ sb)
{
    const int w    = blockIdx.x * 4 + (threadIdx.x >> 6);   // h*1024 + s
    const int lane = threadIdx.x & 63;
    const int s = w & 1023;
    const int h = w >> 10;
    const float diff = pbv[h*64 + lane] - pbu[h*64 + lane];
    const float pv = bf2f(p[(size_t)(h*TT + s)*64 + lane]);
    float val = diff * pv;
#pragma unroll
    for (int off = 32; off; off >>= 1) val += __shfl_xor(val, off);
    if (lane < BB)
        sb[(size_t)(lane*HH + h)*TT + s] = (val * 0.125f + mask[lane*TT + s]) * LOG2E;
}

// ---------------------------------------------------------------------------
// Flash attention v8 (round-8 verified, 81µs): unroll-2 ping-pong pipeline,
// fixed-basis softmax, bf16 hi/lo ao output. (256,3) — unified VGPR+AGPR
// ~148 regs; tighter bounds spill catastrophically (rounds 6/12).
// ---------------------------------------------------------------------------
#define ATTN_GLOAD(tile) do { \
  _Pragma("unroll") for (int it=0; it<2; ++it){ \
    int idx = (it*256+tid)*8; int row_ = idx>>6, col_ = idx&63; \
    kh[it] = *(const s8*)(kb + (size_t)((tile)*64+row_)*64 + col_); \
    vh[it] = *(const s8*)(vtb + (size_t)row_*TT + (tile)*64 + col_); } } while(0)

#define ATTN_SSTORE(buf) do { \
  _Pragma("unroll") for (int it=0; it<2; ++it){ \
    int idx = (it*256+tid)*8; int row_ = idx>>6, col_ = idx&63; \
    int off_ = (row_*128 + col_*2) ^ ((row_&7)<<4); \
    *(s8*)((char*)Ks[(buf)] + off_) = kh[it]; \
    *(s8*)((char*)Vt[(buf)] + off_) = vh[it]; } } while(0)

#define ATTN_QK(buf, scv) do { \
  _Pragma("unroll") for (int j=0;j<4;j++){ \
    int srow_ = j*16+lm; \
    s8 kf0 = *(const s8*)((char*)Ks[(buf)] + ((srow_*128 + lg*16) ^ ((srow_&7)<<4))); \
    s8 kf1 = *(const s8*)((char*)Ks[(buf)] + ((srow_*128 + 64 + lg*16) ^ ((srow_&7)<<4))); \
    scv[j] = __builtin_amdgcn_mfma_f32_16x16x32_bf16(kf0, qf[0], scv[j], 0,0,0); \
    scv[j] = __builtin_amdgcn_mfma_f32_16x16x32_bf16(kf1, qf[1], scv[j], 0,0,0); } } while(0)

#define ATTN_STEP(i, CUR, SCUR, SNXT) do { \
    if ((i) < 15) ATTN_SSTORE((CUR)^1); \
    if ((i) < 14) ATTN_GLOAD((i)+2); \
    __syncthreads(); \
    f4 sbf[4]; \
    _Pragma("unroll") for (int j=0;j<4;j++) sbf[j] = *(const f4*)(sbb + (i)*64 + 16*j + 4*lg); \
    if ((i) < 15){ \
        _Pragma("unroll") for (int j=0;j<4;j++) SNXT[j] = (f4){0.f,0.f,0.f,0.f}; \
        __builtin_amdgcn_s_setprio(1); \
        ATTN_QK((CUR)^1, SNXT); \
        __builtin_amdgcn_s_setprio(0); \
    } \
    s8 vtf[4][2]; \
    _Pragma("unroll") for (int n=0;n<4;n++){ \
        int drow_ = n*16 + lm; \
        _Pragma("unroll") for (int c=0;c<2;c++) \
            vtf[n][c] = *(const s8*)((char*)Vt[(CUR)] + ((drow_*128 + c*64 + lg*16) ^ ((drow_&7)<<4))); \
    } \
    f4 p[4]; \
    _Pragma("unroll") for (int j=0;j<4;j++) \
        _Pragma("unroll") for (int r=0;r<4;r++) \
            p[j][r] = __builtin_exp2f(SCUR[j][r]*SCL + sbf[j][r]); \
    lsum4 += (p[0] + p[1]) + (p[2] + p[3]); \
    _Pragma("unroll") for (int j=0;j<4;j++){ \
        u32x2 w_; \
        w_[0] = cvt_pk(p[j][0], p[j][1]); \
        w_[1] = cvt_pk(p[j][2], p[j][3]); \
        *(u32x2*)((char*)Ps + ((prow*128 + (16*j + 4*lg)*2) ^ ((prow&7)<<4))) = w_; \
    } \
    s8 pf0 = *(const s8*)((char*)Ps + ((prow*128 +  0 + lg*16) ^ ((prow&7)<<4))); \
    s8 pf1 = *(const s8*)((char*)Ps + ((prow*128 + 64 + lg*16) ^ ((prow&7)<<4))); \
    __builtin_amdgcn_s_setprio(1); \
    _Pragma("unroll") for (int n=0;n<4;n++){ \
        oacc[n] = __builtin_amdgcn_mfma_f32_16x16x32_bf16(vtf[n][0], pf0, oacc[n], 0,0,0); \
        oacc[n] = __builtin_amdgcn_mfma_f32_16x16x32_bf16(vtf[n][1], pf1, oacc[n], 0,0,0); \
    } \
    __builtin_amdgcn_s_setprio(0); \
    __syncthreads(); \
} while(0)

__global__ __launch_bounds__(256,3) void attn8(const u16* __restrict__ q,
                                               const u16* __restrict__ kp,
                                               const u16* __restrict__ vt,
                                               const float* __restrict__ sb,
                                               u16* __restrict__ aoh,
                                               u16* __restrict__ aol)
{
    __shared__ __align__(16) u16 Ks[2][64*64];
    __shared__ __align__(16) u16 Vt[2][64*64];
    __shared__ __align__(16) u16 Ps[64*64];

    const int tid = threadIdx.x;
    const int wid = tid>>6, lane = tid&63, lm = lane&15, lg = lane>>4;
    const int bid = blockIdx.x;
    const int xcd = bid & 7, slot = bid >> 3;
    const int bh = xcd + 8*(slot >> 4);      // 0..127
    const int qt = slot & 15;
    const int t0 = qt*64;
    const int b = bh >> 3, h = bh & 7;
    const u16* qb  = q  + (size_t)bh*TT*64;
    const u16* kb  = kp + (size_t)bh*TT*64;
    const u16* vtb = vt + (size_t)bh*DD*TT;   // [d][t]
    const float* sbb = sb + (size_t)bh*TT;

    s8 qf[2];
    qf[0] = *(const s8*)(qb + (size_t)(t0 + wid*16 + lm)*64 + lg*8);
    qf[1] = *(const s8*)(qb + (size_t)(t0 + wid*16 + lm)*64 + 32 + lg*8);

    f4 lsum4 = (f4){0.f,0.f,0.f,0.f};
    f4 oacc[4];
#pragma unroll
    for (int n=0;n<4;n++) oacc[n] = (f4){0.f,0.f,0.f,0.f};
    f4 scA[4], scB[4];

    const float SCL = 0.125f * LOG2E;
    const int prow = wid*16 + lm;

    s8 kh[2], vh[2];

    ATTN_GLOAD(0);
    ATTN_SSTORE(0);
    ATTN_GLOAD(1);
    __syncthreads();
#pragma unroll
    for (int j=0;j<4;j++) scA[j] = (f4){0.f,0.f,0.f,0.f};
    ATTN_QK(0, scA);

    for (int ii=0; ii<8; ++ii){
        ATTN_STEP(2*ii,   0, scA, scB);
        ATTN_STEP(2*ii+1, 1, scB, scA);
    }

    float ls = (lsum4[0]+lsum4[1]) + (lsum4[2]+lsum4[3]);
    ls += __shfl_xor(ls, 16);
    ls += __shfl_xor(ls, 32);
    const float inv = 1.f / ls;
    const size_t row = (size_t)(b*TT + t0 + wid*16 + lm)*NF + h*64;
#pragma unroll
    for (int n=0; n<4; ++n){
        f4 o = oacc[n] * inv;
        u32 h0 = cvt_pk(o[0], o[1]);
        u32 h1 = cvt_pk(o[2], o[3]);
        u32 l0 = cvt_pk(o[0]-lo_bf(h0), o[1]-hi_bf(h0));
        u32 l1 = cvt_pk(o[2]-lo_bf(h1), o[3]-hi_bf(h1));
        *(u32x2*)(&aoh[row + n*16 + lg*4]) = (u32x2){h0,h1};
        *(u32x2*)(&aol[row + n*16 + lg*4]) = (u32x2){l0,l1};
    }
}

// ---------------------------------------------------------------------------
extern "C" void kernel_launch(void* const* d_in, const int* in_sizes, int n_in,
                              void* d_out, int out_size, void* d_ws, size_t ws_size,
                              hipStream_t stream)
{
    const float* query   = (const float*)d_in[0];
    const float* key     = (const float*)d_in[1];
    const float* value   = (const float*)d_in[2];
    const float* pos_emb = (const float*)d_in[3];
    const float* mask    = (const float*)d_in[4];
    const float* Wq   = (const float*)d_in[5];
    const float* bq   = (const float*)d_in[6];
    const float* Wk   = (const float*)d_in[7];
    const float* bk   = (const float*)d_in[8];
    const float* Wv   = (const float*)d_in[9];
    const float* bv   = (const float*)d_in[10];
    const float* Wo   = (const float*)d_in[11];
    const float* bo   = (const float*)d_in[12];
    const float* Wpos = (const float*)d_in[13];
    const float* pbu  = (const float*)d_in[14];
    const float* pbv  = (const float*)d_in[15];
    float* out = (float*)d_out;

    char* ws = (char*)d_ws;
    size_t o = 0;
    u16* wtq  = (u16*)(ws + o); o += (size_t)NF*NF*2;
    u16* wtk  = (u16*)(ws + o); o += (size_t)NF*NF*2;
    u16* wtv  = (u16*)(ws + o); o += (size_t)NF*NF*2;
    u16* wtp  = (u16*)(ws + o); o += (size_t)NF*NF*2;
    u16* wohi = (u16*)(ws + o); o += (size_t)NF*NF*2;
    u16* wolo = (u16*)(ws + o); o += (size_t)NF*NF*2;
    u16* p_ws  = (u16*)(ws + o); o += (size_t)HH*TT*DD*2;
    u16* q_ws  = (u16*)(ws + o); o += (size_t)BB*HH*TT*DD*2;
    u16* kp_ws = (u16*)(ws + o); o += (size_t)BB*HH*TT*DD*2;
    u16* vt_ws = (u16*)(ws + o); o += (size_t)BB*HH*TT*DD*2;
    float* sb_ws = (float*)(ws + o); o += (size_t)BB*HH*TT*4;
    u16* aoh_ws = (u16*)(ws + o); o += (size_t)BB*TT*NF*2;
    u16* aol_ws = (u16*)(ws + o); o += (size_t)BB*TT*NF*2;

    const dim3 blk(256);

    prep_w<<<dim3(16,16,5), blk, 0, stream>>>(Wq, Wk, Wv, Wpos, Wo,
                                              wtq, wtk, wtv, wtp, wohi, wolo);
    // p = pos_emb @ Wpos -> bf16 (H,T,D)
    gemm_bf16<0><<<dim3(TT/128, 4), blk, 0, stream>>>(pos_emb, wtp, p_ws);
    // sb (reads only p, pbu/pbv, mask)
    sbias2<<<dim3(HH*TT/4), blk, 0, stream>>>(p_ws, pbu, pbv, mask, sb_ws);
    // merged q / kp / vt projections (single-barrier load-ahead pipeline)
    qkv_gemm<<<dim3(BB*TT/128, 4, 3), blk, 0, stream>>>(
        query, key, value, wtq, wtk, wtv, bq, bk, bv, p_ws, pbu,
        q_ws, kp_ws, vt_ws);
    // fused attention -> ao bf16 hi/lo
    attn8<<<dim3(BB*HH*TT/64), blk, 0, stream>>>(q_ws, kp_ws, vt_ws, sb_ws, aoh_ws, aol_ws);
    // out = (aoh+aol) @ (Wohi+Wolo) + bo
    gemm_final<<<dim3(BB*TT/128, 4), blk, 0, stream>>>(aoh_ws, aol_ws, wohi, wolo, bo, out);
}

// Round 15
// 179.369 us; speedup vs baseline: 1.1178x; 1.1178x over previous
//
#include <hip/hip_runtime.h>

#define BB 16
#define TT 1024
#define HH 8
#define DD 64
#define NF 512

typedef __attribute__((ext_vector_type(4))) float f4;
typedef __attribute__((ext_vector_type(8))) short s8;
typedef __attribute__((ext_vector_type(2))) unsigned int u32x2;
typedef unsigned short u16;
typedef unsigned int u32;

#define LOG2E 1.4426950408889634f

__device__ __forceinline__ u16 f2bf(float x){
    unsigned int u = __builtin_bit_cast(unsigned int, x);
    u = (u + 0x7FFFu + ((u >> 16) & 1u)) >> 16;
    return (u16)u;
}
__device__ __forceinline__ float bf2f(u16 h){
    unsigned int u = ((unsigned int)h) << 16;
    return __builtin_bit_cast(float, u);
}
__device__ __forceinline__ u32 cvt_pk(float a, float b){
    u32 r; asm("v_cvt_pk_bf16_f32 %0, %1, %2" : "=v"(r) : "v"(a), "v"(b)); return r;
}
__device__ __forceinline__ float lo_bf(u32 p){ return __builtin_bit_cast(float, p << 16); }
__device__ __forceinline__ float hi_bf(u32 p){ return __builtin_bit_cast(float, p & 0xFFFF0000u); }

// ---------------------------------------------------------------------------
// Weight prep: Wt[n][k] = bf16(W[k][n]) for Wq,Wk,Wv,Wpos; Wo -> hi/lo pair.
// ---------------------------------------------------------------------------
__global__ __launch_bounds__(256) void prep_w(const float* __restrict__ Wq,
    const float* __restrict__ Wk, const float* __restrict__ Wv,
    const float* __restrict__ Wpos, const float* __restrict__ Wo,
    u16* __restrict__ wtq, u16* __restrict__ wtk, u16* __restrict__ wtv,
    u16* __restrict__ wtp, u16* __restrict__ wohi, u16* __restrict__ wolo)
{
    __shared__ float tile[32][33];
    const int which = blockIdx.z;
    const float* W = which==0?Wq:which==1?Wk:which==2?Wv:which==3?Wpos:Wo;
    const int n0 = blockIdx.x*32, k0 = blockIdx.y*32;
    const int tc = threadIdx.x & 31, tr = threadIdx.x >> 5;
#pragma unroll
    for (int i=0;i<4;i++){ int r = tr + i*8; tile[r][tc] = W[(size_t)(k0+r)*NF + n0+tc]; }
    __syncthreads();
#pragma unroll
    for (int i=0;i<4;i++){
        int n = tr + i*8, k = tc;
        float val = tile[k][n];
        u16 hi = f2bf(val);
        size_t off = (size_t)(n0+n)*NF + k0+k;
        if (which==0) wtq[off]=hi; else if (which==1) wtk[off]=hi;
        else if (which==2) wtv[off]=hi; else if (which==3) wtp[off]=hi;
        else { wohi[off]=hi; wolo[off]=f2bf(val - bf2f(hi)); }
    }
}

// ---------------------------------------------------------------------------
// bf16 MFMA GEMM, 128x128 tile, BK=64, 4 waves. XOR-swizzled LDS.
// MODE 0: out p_ws[(h*T+t)*64+d]; MODE 2: bhtd bf16 +bias +padd;
// MODE 3: V transposed out[((bh)*64+d)*T + t] +bias;
// MODE 5: bhtd bf16 +bias +pos_bias_u[h][d]  (q projection, u folded in).
// ---------------------------------------------------------------------------
template<int MODE>
__global__ __launch_bounds__(256) void gemm_bf16(const float* __restrict__ A,
                                                 const u16* __restrict__ Wt,
                                                 const float* __restrict__ bias,
                                                 const u16* __restrict__ padd,
                                                 const float* __restrict__ pbias,
                                                 u16* __restrict__ out)
{
    __shared__ __align__(16) u16 As[128*64];
    __shared__ __align__(16) u16 Bs[128*64];
    const int tid = threadIdx.x;
    const int row0 = blockIdx.x*128, col0 = blockIdx.y*128;
    const int wid = tid>>6, lane = tid&63, lm = lane&15, lg = lane>>4;
    const int wm = wid>>1, wn = wid&1;

    f4 acc[4][4];
#pragma unroll
    for (int i=0;i<4;i++)
#pragma unroll
        for (int j=0;j<4;j++) acc[i][j] = (f4){0.f,0.f,0.f,0.f};

    for (int k0=0;k0<NF;k0+=64){
        f4 areg[8]; s8 breg[4];
#pragma unroll
        for (int it=0; it<8; ++it){
            int idx = (it*256 + tid)*4;
            int m = idx>>6, k = idx&63;
            areg[it] = *(const f4*)(&A[(size_t)(row0+m)*NF + k0 + k]);
        }
#pragma unroll
        for (int it=0; it<4; ++it){
            int idx = (it*256 + tid)*8;
            int n = idx>>6, k = idx&63;
            breg[it] = *(const s8*)(&Wt[(size_t)(col0+n)*NF + k0 + k]);
        }
        __syncthreads();
#pragma unroll
        for (int it=0; it<8; ++it){
            int idx = (it*256+tid)*4;
            int m = idx>>6, k = idx&63;
            u32x2 pk;
            pk[0] = cvt_pk(areg[it][0], areg[it][1]);
            pk[1] = cvt_pk(areg[it][2], areg[it][3]);
            *(u32x2*)((char*)As + ((m*128 + k*2) ^ ((m&7)<<4))) = pk;
        }
#pragma unroll
        for (int it=0; it<4; ++it){
            int idx = (it*256+tid)*8;
            int n = idx>>6, k = idx&63;
            *(s8*)((char*)Bs + ((n*128 + k*2) ^ ((n&7)<<4))) = breg[it];
        }
        __syncthreads();
        s8 af[4][2], bf[4][2];
#pragma unroll
        for (int i=0;i<4;i++){
            int m = wm*64 + i*16 + lm;
#pragma unroll
            for (int c=0;c<2;c++)
                af[i][c] = *(const s8*)((char*)As + ((m*128 + c*64 + lg*16) ^ ((m&7)<<4)));
        }
#pragma unroll
        for (int j=0;j<4;j++){
            int n = wn*64 + j*16 + lm;
#pragma unroll
            for (int c=0;c<2;c++)
                bf[j][c] = *(const s8*)((char*)Bs + ((n*128 + c*64 + lg*16) ^ ((n&7)<<4)));
        }
#pragma unroll
        for (int i=0;i<4;i++)
#pragma unroll
            for (int j=0;j<4;j++)
#pragma unroll
                for (int c=0;c<2;c++)
                    acc[i][j] = __builtin_amdgcn_mfma_f32_16x16x32_bf16(af[i][c], bf[j][c], acc[i][j], 0,0,0);
    }

#pragma unroll
    for (int i=0;i<4;i++){
#pragma unroll
        for (int j=0;j<4;j++){
#pragma unroll
            for (int r=0;r<4;r++){
                const int m = row0 + wm*64 + i*16 + lg*4 + r;
                const int n = col0 + wn*64 + j*16 + lm;
                float val = acc[i][j][r];
                const int hh = n>>6, dd = n&63;
                if (MODE == 0){
                    out[(size_t)(hh*TT + m)*64 + dd] = f2bf(val);
                } else {
                    val += bias[n];
                    const int b_ = m>>10, t_ = m&1023;
                    if (MODE == 2) val += bf2f(padd[(size_t)(hh*TT + t_)*64 + dd]);
                    if (MODE == 5) val += pbias[n];   // pos_bias_u[h*64+d]
                    if (MODE == 3)
                        out[(((size_t)(b_*HH+hh))*DD + dd)*TT + t_] = f2bf(val);
                    else
                        out[((size_t)(b_*HH+hh)*TT + t_)*64 + dd] = f2bf(val);
                }
            }
        }
    }
}

// ---------------------------------------------------------------------------
// Final GEMM: out = [aoh+aol](bf16 hi/lo) @ [Wo hi/lo] + bo, 3 MFMA terms.
// A comes pre-split from attn -> staging is pure s8 loads (no cvt chain).
// ---------------------------------------------------------------------------
__global__ __launch_bounds__(256) void gemm_final(const u16* __restrict__ Ahg,
    const u16* __restrict__ Alg,
    const u16* __restrict__ Bhg, const u16* __restrict__ Blg,
    const float* __restrict__ bias, float* __restrict__ out)
{
    __shared__ __align__(16) u16 Ah[128*64];
    __shared__ __align__(16) u16 Al[128*64];
    __shared__ __align__(16) u16 Bh[128*64];
    __shared__ __align__(16) u16 Bl[128*64];
    const int tid = threadIdx.x;
    const int row0 = blockIdx.x*128, col0 = blockIdx.y*128;
    const int wid = tid>>6, lane = tid&63, lm = lane&15, lg = lane>>4;
    const int wm = wid>>1, wn = wid&1;

    f4 acc[4][4];
#pragma unroll
    for (int i=0;i<4;i++)
#pragma unroll
        for (int j=0;j<4;j++) acc[i][j] = (f4){0.f,0.f,0.f,0.f};

    for (int k0=0;k0<NF;k0+=64){
        s8 ahreg[4], alreg[4], bhreg[4], blreg[4];
#pragma unroll
        for (int it=0; it<4; ++it){
            int idx = (it*256 + tid)*8;
            int m = idx>>6, k = idx&63;
            ahreg[it] = *(const s8*)(&Ahg[(size_t)(row0+m)*NF + k0 + k]);
            alreg[it] = *(const s8*)(&Alg[(size_t)(row0+m)*NF + k0 + k]);
            bhreg[it] = *(const s8*)(&Bhg[(size_t)(col0+m)*NF + k0 + k]);
            blreg[it] = *(const s8*)(&Blg[(size_t)(col0+m)*NF + k0 + k]);
        }
        __syncthreads();
#pragma unroll
        for (int it=0; it<4; ++it){
            int idx = (it*256+tid)*8;
            int m = idx>>6, k = idx&63;
            int off = (m*128 + k*2) ^ ((m&7)<<4);
            *(s8*)((char*)Ah + off) = ahreg[it];
            *(s8*)((char*)Al + off) = alreg[it];
            *(s8*)((char*)Bh + off) = bhreg[it];
            *(s8*)((char*)Bl + off) = blreg[it];
        }
        __syncthreads();
#pragma unroll
        for (int c=0;c<2;c++){
            s8 ah[4], al[4], bh4[4], bl4[4];
#pragma unroll
            for (int i=0;i<4;i++){
                int m = wm*64 + i*16 + lm;
                int off = (m*128 + c*64 + lg*16) ^ ((m&7)<<4);
                ah[i] = *(const s8*)((char*)Ah + off);
                al[i] = *(const s8*)((char*)Al + off);
            }
#pragma unroll
            for (int j=0;j<4;j++){
                int n = wn*64 + j*16 + lm;
                int off = (n*128 + c*64 + lg*16) ^ ((n&7)<<4);
                bh4[j] = *(const s8*)((char*)Bh + off);
                bl4[j] = *(const s8*)((char*)Bl + off);
            }
#pragma unroll
            for (int i=0;i<4;i++)
#pragma unroll
                for (int j=0;j<4;j++){
                    acc[i][j] = __builtin_amdgcn_mfma_f32_16x16x32_bf16(al[i], bh4[j], acc[i][j], 0,0,0);
                    acc[i][j] = __builtin_amdgcn_mfma_f32_16x16x32_bf16(ah[i], bl4[j], acc[i][j], 0,0,0);
                    acc[i][j] = __builtin_amdgcn_mfma_f32_16x16x32_bf16(ah[i], bh4[j], acc[i][j], 0,0,0);
                }
        }
    }

#pragma unroll
    for (int i=0;i<4;i++)
#pragma unroll
        for (int j=0;j<4;j++)
#pragma unroll
            for (int r=0;r<4;r++){
                const int m = row0 + wm*64 + i*16 + lg*4 + r;
                const int n = col0 + wn*64 + j*16 + lm;
                out[(size_t)m*NF + n] = acc[i][j][r] + bias[n];
            }
}

// ---------------------------------------------------------------------------
// sb[b,h,s] = (((v-u)·p[h,s])/8 + mask[b,s]) * log2(e).  (u·k folded into q.)
// One wave per (h,s); reads only p (1MB, L2-resident) — no kp read.
// ---------------------------------------------------------------------------
__global__ __launch_bounds__(256) void sbias2(const u16* __restrict__ p,
                                              const float* __restrict__ pbu,
                                              const float* __restrict__ pbv,
                                              const float* __restrict__ mask,
                                              float* __restrict__ sb)
{
    const int w    = blockIdx.x * 4 + (threadIdx.x >> 6);   // h*1024 + s
    const int lane = threadIdx.x & 63;
    const int s = w & 1023;
    const int h = w >> 10;
    const float diff = pbv[h*64 + lane] - pbu[h*64 + lane];
    const float pv = bf2f(p[(size_t)(h*TT + s)*64 + lane]);
    float val = diff * pv;
#pragma unroll
    for (int off = 32; off; off >>= 1) val += __shfl_xor(val, off);
    if (lane < BB)
        sb[(size_t)(lane*HH + h)*TT + s] = (val * 0.125f + mask[lane*TT + s]) * LOG2E;
}

// ---------------------------------------------------------------------------
// Flash attention v8 (round-8 verified, 81µs): unroll-2 ping-pong pipeline,
// fixed-basis softmax, bf16 hi/lo ao output. (256,3) — unified VGPR+AGPR
// ~148 regs means 3 blocks/CU is the spill-free occupancy ceiling; tighter
// bounds (rounds 6/12) force arch-VGPR down and spill catastrophically.
// ---------------------------------------------------------------------------
#define ATTN_GLOAD(tile) do { \
  _Pragma("unroll") for (int it=0; it<2; ++it){ \
    int idx = (it*256+tid)*8; int row_ = idx>>6, col_ = idx&63; \
    kh[it] = *(const s8*)(kb + (size_t)((tile)*64+row_)*64 + col_); \
    vh[it] = *(const s8*)(vtb + (size_t)row_*TT + (tile)*64 + col_); } } while(0)

#define ATTN_SSTORE(buf) do { \
  _Pragma("unroll") for (int it=0; it<2; ++it){ \
    int idx = (it*256+tid)*8; int row_ = idx>>6, col_ = idx&63; \
    int off_ = (row_*128 + col_*2) ^ ((row_&7)<<4); \
    *(s8*)((char*)Ks[(buf)] + off_) = kh[it]; \
    *(s8*)((char*)Vt[(buf)] + off_) = vh[it]; } } while(0)

#define ATTN_QK(buf, scv) do { \
  _Pragma("unroll") for (int j=0;j<4;j++){ \
    int srow_ = j*16+lm; \
    s8 kf0 = *(const s8*)((char*)Ks[(buf)] + ((srow_*128 + lg*16) ^ ((srow_&7)<<4))); \
    s8 kf1 = *(const s8*)((char*)Ks[(buf)] + ((srow_*128 + 64 + lg*16) ^ ((srow_&7)<<4))); \
    scv[j] = __builtin_amdgcn_mfma_f32_16x16x32_bf16(kf0, qf[0], scv[j], 0,0,0); \
    scv[j] = __builtin_amdgcn_mfma_f32_16x16x32_bf16(kf1, qf[1], scv[j], 0,0,0); } } while(0)

#define ATTN_STEP(i, CUR, SCUR, SNXT) do { \
    if ((i) < 15) ATTN_SSTORE((CUR)^1); \
    if ((i) < 14) ATTN_GLOAD((i)+2); \
    __syncthreads(); \
    f4 sbf[4]; \
    _Pragma("unroll") for (int j=0;j<4;j++) sbf[j] = *(const f4*)(sbb + (i)*64 + 16*j + 4*lg); \
    if ((i) < 15){ \
        _Pragma("unroll") for (int j=0;j<4;j++) SNXT[j] = (f4){0.f,0.f,0.f,0.f}; \
        __builtin_amdgcn_s_setprio(1); \
        ATTN_QK((CUR)^1, SNXT); \
        __builtin_amdgcn_s_setprio(0); \
    } \
    s8 vtf[4][2]; \
    _Pragma("unroll") for (int n=0;n<4;n++){ \
        int drow_ = n*16 + lm; \
        _Pragma("unroll") for (int c=0;c<2;c++) \
            vtf[n][c] = *(const s8*)((char*)Vt[(CUR)] + ((drow_*128 + c*64 + lg*16) ^ ((drow_&7)<<4))); \
    } \
    f4 p[4]; \
    _Pragma("unroll") for (int j=0;j<4;j++) \
        _Pragma("unroll") for (int r=0;r<4;r++) \
            p[j][r] = __builtin_exp2f(SCUR[j][r]*SCL + sbf[j][r]); \
    lsum4 += (p[0] + p[1]) + (p[2] + p[3]); \
    _Pragma("unroll") for (int j=0;j<4;j++){ \
        u32x2 w_; \
        w_[0] = cvt_pk(p[j][0], p[j][1]); \
        w_[1] = cvt_pk(p[j][2], p[j][3]); \
        *(u32x2*)((char*)Ps + ((prow*128 + (16*j + 4*lg)*2) ^ ((prow&7)<<4))) = w_; \
    } \
    s8 pf0 = *(const s8*)((char*)Ps + ((prow*128 +  0 + lg*16) ^ ((prow&7)<<4))); \
    s8 pf1 = *(const s8*)((char*)Ps + ((prow*128 + 64 + lg*16) ^ ((prow&7)<<4))); \
    __builtin_amdgcn_s_setprio(1); \
    _Pragma("unroll") for (int n=0;n<4;n++){ \
        oacc[n] = __builtin_amdgcn_mfma_f32_16x16x32_bf16(vtf[n][0], pf0, oacc[n], 0,0,0); \
        oacc[n] = __builtin_amdgcn_mfma_f32_16x16x32_bf16(vtf[n][1], pf1, oacc[n], 0,0,0); \
    } \
    __builtin_amdgcn_s_setprio(0); \
    __syncthreads(); \
} while(0)

__global__ __launch_bounds__(256,3) void attn8(const u16* __restrict__ q,
                                               const u16* __restrict__ kp,
                                               const u16* __restrict__ vt,
                                               const float* __restrict__ sb,
                                               u16* __restrict__ aoh,
                                               u16* __restrict__ aol)
{
    __shared__ __align__(16) u16 Ks[2][64*64];
    __shared__ __align__(16) u16 Vt[2][64*64];
    __shared__ __align__(16) u16 Ps[64*64];

    const int tid = threadIdx.x;
    const int wid = tid>>6, lane = tid&63, lm = lane&15, lg = lane>>4;
    const int bid = blockIdx.x;
    const int xcd = bid & 7, slot = bid >> 3;
    const int bh = xcd + 8*(slot >> 4);      // 0..127
    const int qt = slot & 15;
    const int t0 = qt*64;
    const int b = bh >> 3, h = bh & 7;
    const u16* qb  = q  + (size_t)bh*TT*64;
    const u16* kb  = kp + (size_t)bh*TT*64;
    const u16* vtb = vt + (size_t)bh*DD*TT;   // [d][t]
    const float* sbb = sb + (size_t)bh*TT;

    s8 qf[2];
    qf[0] = *(const s8*)(qb + (size_t)(t0 + wid*16 + lm)*64 + lg*8);
    qf[1] = *(const s8*)(qb + (size_t)(t0 + wid*16 + lm)*64 + 32 + lg*8);

    f4 lsum4 = (f4){0.f,0.f,0.f,0.f};
    f4 oacc[4];
#pragma unroll
    for (int n=0;n<4;n++) oacc[n] = (f4){0.f,0.f,0.f,0.f};
    f4 scA[4], scB[4];

    const float SCL = 0.125f * LOG2E;
    const int prow = wid*16 + lm;

    s8 kh[2], vh[2];

    ATTN_GLOAD(0);
    ATTN_SSTORE(0);
    ATTN_GLOAD(1);
    __syncthreads();
#pragma unroll
    for (int j=0;j<4;j++) scA[j] = (f4){0.f,0.f,0.f,0.f};
    ATTN_QK(0, scA);

    for (int ii=0; ii<8; ++ii){
        ATTN_STEP(2*ii,   0, scA, scB);
        ATTN_STEP(2*ii+1, 1, scB, scA);
    }

    float ls = (lsum4[0]+lsum4[1]) + (lsum4[2]+lsum4[3]);
    ls += __shfl_xor(ls, 16);
    ls += __shfl_xor(ls, 32);
    const float inv = 1.f / ls;
    const size_t row = (size_t)(b*TT + t0 + wid*16 + lm)*NF + h*64;
#pragma unroll
    for (int n=0; n<4; ++n){
        f4 o = oacc[n] * inv;
        u32 h0 = cvt_pk(o[0], o[1]);
        u32 h1 = cvt_pk(o[2], o[3]);
        u32 l0 = cvt_pk(o[0]-lo_bf(h0), o[1]-hi_bf(h0));
        u32 l1 = cvt_pk(o[2]-lo_bf(h1), o[3]-hi_bf(h1));
        *(u32x2*)(&aoh[row + n*16 + lg*4]) = (u32x2){h0,h1};
        *(u32x2*)(&aol[row + n*16 + lg*4]) = (u32x2){l0,l1};
    }
}

// ---------------------------------------------------------------------------
extern "C" void kernel_launch(void* const* d_in, const int* in_sizes, int n_in,
                              void* d_out, int out_size, void* d_ws, size_t ws_size,
                              hipStream_t stream)
{
    const float* query   = (const float*)d_in[0];
    const float* key     = (const float*)d_in[1];
    const float* value   = (const float*)d_in[2];
    const float* pos_emb = (const float*)d_in[3];
    const float* mask    = (const float*)d_in[4];
    const float* Wq   = (const float*)d_in[5];
    const float* bq   = (const float*)d_in[6];
    const float* Wk   = (const float*)d_in[7];
    const float* bk   = (const float*)d_in[8];
    const float* Wv   = (const float*)d_in[9];
    const float* bv   = (const float*)d_in[10];
    const float* Wo   = (const float*)d_in[11];
    const float* bo   = (const float*)d_in[12];
    const float* Wpos = (const float*)d_in[13];
    const float* pbu  = (const float*)d_in[14];
    const float* pbv  = (const float*)d_in[15];
    float* out = (float*)d_out;

    char* ws = (char*)d_ws;
    size_t o = 0;
    u16* wtq  = (u16*)(ws + o); o += (size_t)NF*NF*2;
    u16* wtk  = (u16*)(ws + o); o += (size_t)NF*NF*2;
    u16* wtv  = (u16*)(ws + o); o += (size_t)NF*NF*2;
    u16* wtp  = (u16*)(ws + o); o += (size_t)NF*NF*2;
    u16* wohi = (u16*)(ws + o); o += (size_t)NF*NF*2;
    u16* wolo = (u16*)(ws + o); o += (size_t)NF*NF*2;
    u16* p_ws  = (u16*)(ws + o); o += (size_t)HH*TT*DD*2;
    u16* q_ws  = (u16*)(ws + o); o += (size_t)BB*HH*TT*DD*2;
    u16* kp_ws = (u16*)(ws + o); o += (size_t)BB*HH*TT*DD*2;
    u16* vt_ws = (u16*)(ws + o); o += (size_t)BB*HH*TT*DD*2;
    float* sb_ws = (float*)(ws + o); o += (size_t)BB*HH*TT*4;
    u16* aoh_ws = (u16*)(ws + o); o += (size_t)BB*TT*NF*2;
    u16* aol_ws = (u16*)(ws + o); o += (size_t)BB*TT*NF*2;

    const dim3 blk(256);

    prep_w<<<dim3(16,16,5), blk, 0, stream>>>(Wq, Wk, Wv, Wpos, Wo,
                                              wtq, wtk, wtv, wtp, wohi, wolo);
    // p = pos_emb @ Wpos -> bf16 (H,T,D)
    gemm_bf16<0><<<dim3(TT/128, 4), blk, 0, stream>>>(pos_emb, wtp, nullptr, nullptr, nullptr, p_ws);
    // sb (reads only p, pbu/pbv, mask — no kp dependency)
    sbias2<<<dim3(HH*TT/4), blk, 0, stream>>>(p_ws, pbu, pbv, mask, sb_ws);
    // q = query@Wq + bq + pos_bias_u   (u folded into q)
    gemm_bf16<5><<<dim3(BB*TT/128, 4), blk, 0, stream>>>(query, wtq, bq, nullptr, pbu, q_ws);
    // kp = key@Wk + bk + p
    gemm_bf16<2><<<dim3(BB*TT/128, 4), blk, 0, stream>>>(key,   wtk, bk, p_ws, nullptr, kp_ws);
    // vt = (value@Wv + bv)^T per (b,h)
    gemm_bf16<3><<<dim3(BB*TT/128, 4), blk, 0, stream>>>(value, wtv, bv, nullptr, nullptr, vt_ws);
    // fused attention -> ao bf16 hi/lo
    attn8<<<dim3(BB*HH*TT/64), blk, 0, stream>>>(q_ws, kp_ws, vt_ws, sb_ws, aoh_ws, aol_ws);
    // out = (aoh+aol) @ (Wohi+Wolo) + bo
    gemm_final<<<dim3(BB*TT/128, 4), blk, 0, stream>>>(aoh_ws, aol_ws, wohi, wolo, bo, out);
}